// Round 23
// baseline (136.615 us; speedup 1.0000x reference)
//
#include <hip/hip_runtime.h>
#include <math.h>

#define D_MODEL 1024
#define D_INNER 2048
#define D_STATE 64
#define SEQ     2048
#define BATCH   2
#define NROWS   (BATCH*SEQ)   // 4096

typedef unsigned short ushort_t;
typedef unsigned int uint_t;
typedef __attribute__((ext_vector_type(8))) unsigned short ushort8_t;

__device__ __forceinline__ float silu_f(float x) { return x / (1.f + __expf(-x)); }
__device__ __forceinline__ ushort_t f2bf(float f) {
    uint_t u = __float_as_uint(f);
    uint_t r = (u + 0x7FFFu + ((u >> 16) & 1u)) >> 16;   // RNE
    return (ushort_t)r;
}
__device__ __forceinline__ float bf2f(ushort_t u) {
    return __uint_as_float(((uint_t)u) << 16);
}

typedef __attribute__((address_space(1))) const void gvoid_t;
typedef __attribute__((address_space(3))) void lvoid_t;

template<int N> __device__ __forceinline__ void wait_vmcnt() {
    if constexpr (N == 0)      asm volatile("s_waitcnt vmcnt(0)" ::: "memory");
    else if constexpr (N == 3) asm volatile("s_waitcnt vmcnt(3)" ::: "memory");
    else if constexpr (N == 6) asm volatile("s_waitcnt vmcnt(6)" ::: "memory");
    else static_assert(N == 0, "unsupported vmcnt");
}

// ---------------------------------------------------------------------------
// Batched f32 -> bf16 conversion: 5 (src,dst) ranges in one launch.
// ---------------------------------------------------------------------------
__global__ __launch_bounds__(256) void cvt5_kernel(
    const float* __restrict__ s0, ushort_t* __restrict__ d0, int b0,
    const float* __restrict__ s1, ushort_t* __restrict__ d1, int b1,
    const float* __restrict__ s2, ushort_t* __restrict__ d2, int b2,
    const float* __restrict__ s3, ushort_t* __restrict__ d3, int b3,
    const float* __restrict__ s4, ushort_t* __restrict__ d4, int b4)
{
    int blk = blockIdx.x;
    const float* s; ushort_t* d;
    if (blk < b0)                    { s = s0; d = d0; }
    else if (blk < b0 + b1)          { s = s1; d = d1; blk -= b0; }
    else if (blk < b0 + b1 + b2)     { s = s2; d = d2; blk -= b0 + b1; }
    else if (blk < b0 + b1 + b2 + b3){ s = s3; d = d3; blk -= b0 + b1 + b2; }
    else                             { s = s4; d = d4; blk -= b0 + b1 + b2 + b3; }
    int i = (blk * 256 + threadIdx.x) * 4;
    float4 v = *reinterpret_cast<const float4*>(s + i);
    ushort4 o;
    o.x = f2bf(v.x); o.y = f2bf(v.y); o.z = f2bf(v.z); o.w = f2bf(v.w);
    *reinterpret_cast<ushort4*>(d + i) = o;
}

// ---------------------------------------------------------------------------
// in_proj GEMM: 8-wave 256x128 depth-2, 2-D raster (measured-best).
// ---------------------------------------------------------------------------
__global__ __launch_bounds__(512, 4) void gemm_pipe8_inproj(
    const ushort_t* __restrict__ Abf, const ushort_t* __restrict__ Wbf,
    const float* __restrict__ bias,
    ushort_t* __restrict__ out_x, ushort_t* __restrict__ out_g, int K)
{
    using bf16x8 = __attribute__((ext_vector_type(8))) short;
    using f32x4  = __attribute__((ext_vector_type(4))) float;

    constexpr int BMt  = 256, BNt = 128, BKt = 32;
    constexpr int ABLK = BMt / 16;            // 16
    constexpr int NBLK = (BMt + BNt) / 16;    // 24
    constexpr int TILE = (BMt + BNt) * BKt;   // 24KB
    constexpr int L    = NBLK / 8;            // 3

    __shared__ ushort_t buf[2][TILE];

    const int tid  = threadIdx.x;
    const int lane = tid & 63;
    const int wid  = tid >> 6;
    const int bm   = blockIdx.y * BMt;
    const int bn   = blockIdx.x * BNt;
    const int wr   = (wid >> 1) * 64;
    const int wc   = (wid & 1) * 64;
    const int r16  = lane & 15;
    const int g    = lane >> 4;
    const int srow = lane >> 2;
    const int scg  = ((lane & 3) ^ (srow & 3)) * 8;
    const int rg   = (g ^ (r16 & 3)) * 8;

    f32x4 acc[4][4] = {};

    auto stage = [&](int p, int k0) {
        #pragma unroll
        for (int i = wid; i < NBLK; i += 8) {
            const ushort_t* gsrc;
            if (i < ABLK)
                gsrc = Abf + (size_t)(bm + 16 * i + srow) * K + k0 + scg;
            else
                gsrc = Wbf + (size_t)(bn + 16 * (i - ABLK) + srow) * K + k0 + scg;
            __builtin_amdgcn_global_load_lds((gvoid_t*)gsrc, (lvoid_t*)(&buf[p][i * 512]), 16, 0, 0);
        }
    };

    const int NT = K / BKt;
    stage(0, 0);
    stage(1, BKt);
    wait_vmcnt<L>();
    __builtin_amdgcn_s_barrier();

    for (int t = 0; t < NT; ++t) {
        const ushort_t* Tb = &buf[t & 1][0];
        bf16x8 af[4], bfr[4];
        #pragma unroll
        for (int m = 0; m < 4; ++m)
            af[m] = *reinterpret_cast<const bf16x8*>(
                &Tb[((wr >> 4) + m) * 512 + r16 * 32 + rg]);
        #pragma unroll
        for (int n = 0; n < 4; ++n)
            bfr[n] = *reinterpret_cast<const bf16x8*>(
                &Tb[(ABLK + (wc >> 4) + n) * 512 + r16 * 32 + rg]);

        asm volatile("s_waitcnt lgkmcnt(0)" ::: "memory");
        __builtin_amdgcn_s_barrier();

        if (t + 2 < NT) stage(t & 1, (t + 2) * BKt);

        #pragma unroll
        for (int m = 0; m < 4; ++m)
            #pragma unroll
            for (int n = 0; n < 4; ++n)
                acc[m][n] = __builtin_amdgcn_mfma_f32_16x16x32_bf16(af[m], bfr[n], acc[m][n], 0, 0, 0);

        if (t + 1 < NT) {
            if (t + 2 < NT) wait_vmcnt<L>();
            else            wait_vmcnt<0>();
            __builtin_amdgcn_s_barrier();
        }
    }

    #pragma unroll
    for (int m = 0; m < 4; ++m) {
        int row0 = bm + wr + m * 16 + g * 4;
        #pragma unroll
        for (int n = 0; n < 4; ++n) {
            int col = bn + wc + n * 16 + r16;
            float b = bias[col];
            if (col < D_INNER) {
                #pragma unroll
                for (int jj = 0; jj < 4; ++jj)
                    out_x[(size_t)(row0 + jj) * D_INNER + col] = f2bf(acc[m][n][jj] + b);
            } else {
                int c2 = col - D_INNER;
                #pragma unroll
                for (int jj = 0; jj < 4; ++jj)
                    out_g[(size_t)(row0 + jj) * D_INNER + c2] = f2bf(silu_f(acc[m][n][jj] + b));
            }
        }
    }
}

// ---------------------------------------------------------------------------
// out_proj GEMM: 256-thread depth-2, KH=2, XCD-chunk swizzle (measured-best).
// ---------------------------------------------------------------------------
template <int BMt, int BNt, int KH>
__global__ __launch_bounds__(256) void gemm_pipe(
    const ushort_t* __restrict__ Abf, const ushort_t* __restrict__ Wbf,
    const float* __restrict__ bias,
    float* __restrict__ out0, int M, int N, int K)
{
    using bf16x8 = __attribute__((ext_vector_type(8))) short;
    using f32x4  = __attribute__((ext_vector_type(4))) float;

    constexpr int BKt  = 32 * KH;
    constexpr int MF   = BMt / 32;
    constexpr int NF   = BNt / 32;
    constexpr int ARB  = BMt / 16;
    constexpr int BRB  = BNt / 16;
    constexpr int ABLK = ARB * KH;
    constexpr int NBLK = (ARB + BRB) * KH;
    constexpr int TILE = (BMt + BNt) * BKt;
    constexpr int L    = NBLK / 4;

    __shared__ ushort_t buf[2][TILE];

    const int tid  = threadIdx.x;
    const int lane = tid & 63;
    const int wid  = tid >> 6;

    const int nbn  = N / BNt;
    const int bid  = blockIdx.x;
    const int nb   = (M / BMt) * nbn;
    const int cpx  = nb / 8;
    const int flat = (bid & 7) * cpx + (bid >> 3);
    const int bm   = (flat / nbn) * BMt;
    const int bn   = (flat % nbn) * BNt;

    const int wr   = (wid >> 1) * (BMt / 2);
    const int wc   = (wid & 1) * (BNt / 2);
    const int r16  = lane & 15;
    const int g    = lane >> 4;
    const int srow = lane >> 2;
    const int scg  = ((lane & 3) ^ (srow & 3)) * 8;
    const int rg   = (g ^ (r16 & 3)) * 8;

    f32x4 acc[MF][NF] = {};

    auto stage = [&](int p, int k0) {
        #pragma unroll
        for (int i = wid; i < NBLK; i += 4) {
            const ushort_t* gsrc;
            if (i < ABLK) {
                int kh = i / ARB, rb = i % ARB;
                gsrc = Abf + (size_t)(bm + 16 * rb + srow) * K + k0 + kh * 32 + scg;
            } else {
                int j = i - ABLK;
                int kh = j / BRB, rb = j % BRB;
                gsrc = Wbf + (size_t)(bn + 16 * rb + srow) * K + k0 + kh * 32 + scg;
            }
            __builtin_amdgcn_global_load_lds((gvoid_t*)gsrc, (lvoid_t*)(&buf[p][i * 512]), 16, 0, 0);
        }
    };

    const int NT = K / BKt;
    stage(0, 0);
    stage(1, BKt);
    wait_vmcnt<L>();
    __builtin_amdgcn_s_barrier();

    for (int t = 0; t < NT; ++t) {
        const ushort_t* Tb = &buf[t & 1][0];
        bf16x8 af[MF][KH], bfr[NF][KH];
        #pragma unroll
        for (int kk = 0; kk < KH; ++kk) {
            #pragma unroll
            for (int m = 0; m < MF; ++m)
                af[m][kk] = *reinterpret_cast<const bf16x8*>(
                    &Tb[(kk * ARB + (wr >> 4) + m) * 512 + r16 * 32 + rg]);
            #pragma unroll
            for (int n = 0; n < NF; ++n)
                bfr[n][kk] = *reinterpret_cast<const bf16x8*>(
                    &Tb[(ABLK + kk * BRB + (wc >> 4) + n) * 512 + r16 * 32 + rg]);
        }

        asm volatile("s_waitcnt lgkmcnt(0)" ::: "memory");
        __builtin_amdgcn_s_barrier();

        if (t + 2 < NT) stage(t & 1, (t + 2) * BKt);

        #pragma unroll
        for (int kk = 0; kk < KH; ++kk)
            #pragma unroll
            for (int m = 0; m < MF; ++m)
                #pragma unroll
                for (int n = 0; n < NF; ++n)
                    acc[m][n] = __builtin_amdgcn_mfma_f32_16x16x32_bf16(
                        af[m][kk], bfr[n][kk], acc[m][n], 0, 0, 0);

        if (t + 1 < NT) {
            if (t + 2 < NT) wait_vmcnt<L>();
            else            wait_vmcnt<0>();
            __builtin_amdgcn_s_barrier();
        }
    }

    #pragma unroll
    for (int m = 0; m < MF; ++m) {
        int row0 = bm + wr + m * 16 + g * 4;
        #pragma unroll
        for (int n = 0; n < NF; ++n) {
            int col = bn + wc + n * 16 + r16;
            float b = bias[col];
            #pragma unroll
            for (int jj = 0; jj < 4; ++jj)
                out0[(size_t)(row0 + jj) * N + col] = acc[m][n][jj] + b;
        }
    }
}

// ---------------------------------------------------------------------------
// Causal depthwise conv (D_CONV=4) + SiLU, 8 channels x 4 time-rows/thread
// (ushort8 IO — halves VMEM instruction count vs the 4-channel version).
// Per-element math identical (same tap order, zero-padded invalid taps).
// ---------------------------------------------------------------------------
__global__ __launch_bounds__(256) void conv_silu8_kernel(
    const ushort_t* __restrict__ xssm,
    const float* __restrict__ conv_w,
    const float* __restrict__ conv_b,
    ushort_t* __restrict__ xc)
{
    int idx = blockIdx.x * 256 + threadIdx.x;     // NROWS*D_INNER/32 total
    int cg = idx & (D_INNER / 8 - 1);             // 0..255
    int rg = idx >> 8;                            // 0..1023
    int c  = cg * 8;
    int r4 = rg * 4;
    int s4 = r4 & (SEQ - 1);

    float4 wv[8];
    #pragma unroll
    for (int cc = 0; cc < 8; ++cc)
        wv[cc] = *reinterpret_cast<const float4*>(conv_w + (c + cc) * 4);
    float bias8[8];
    {
        float4 b0 = *reinterpret_cast<const float4*>(conv_b + c);
        float4 b1 = *reinterpret_cast<const float4*>(conv_b + c + 4);
        bias8[0] = b0.x; bias8[1] = b0.y; bias8[2] = b0.z; bias8[3] = b0.w;
        bias8[4] = b1.x; bias8[5] = b1.y; bias8[6] = b1.z; bias8[7] = b1.w;
    }

    float xin[7][8];
    #pragma unroll
    for (int rr = 0; rr < 7; ++rr) {
        if (s4 > 0 || rr >= 3) {
            ushort8_t v = *reinterpret_cast<const ushort8_t*>(
                xssm + (size_t)(r4 + rr - 3) * D_INNER + c);
            #pragma unroll
            for (int j = 0; j < 8; ++j) xin[rr][j] = bf2f(v[j]);
        } else {
            #pragma unroll
            for (int j = 0; j < 8; ++j) xin[rr][j] = 0.f;
        }
    }

    #pragma unroll
    for (int i = 0; i < 4; ++i) {
        float acc[8];
        #pragma unroll
        for (int j = 0; j < 8; ++j) acc[j] = bias8[j];
        #pragma unroll
        for (int dt = 0; dt < 4; ++dt) {
            int rr = i + 3 - dt;
            #pragma unroll
            for (int j = 0; j < 8; ++j)
                acc[j] += (&wv[j].x)[3 - dt] * xin[rr][j];
        }
        ushort8_t h;
        #pragma unroll
        for (int j = 0; j < 8; ++j) h[j] = f2bf(silu_f(acc[j]));
        *reinterpret_cast<ushort8_t*>(xc + (size_t)(r4 + i) * D_INNER + c) = h;
    }
}

// ---------------------------------------------------------------------------
// XB split-K (r22 proven): 256 blocks, partial sums consumed by scan.
// ---------------------------------------------------------------------------
#define BK 32
__global__ __launch_bounds__(128) void xb_mfma(
    const ushort_t* __restrict__ xc, const ushort_t* __restrict__ Bw,
    float* __restrict__ xbp)
{
    using bf16x8 = __attribute__((ext_vector_type(8))) short;
    using f32x4  = __attribute__((ext_vector_type(4))) float;

    __shared__ ushort_t As[32 * BK];
    __shared__ ushort_t Bs[64 * BK];

    const int tid  = threadIdx.x;
    const int lane = tid & 63;
    const int wid  = tid >> 6;
    const int kh   = blockIdx.x & 1;
    const int bm   = (blockIdx.x >> 1) * 32;
    const int kb   = kh * (D_INNER / 2);
    const int r16  = lane & 15;
    const int g    = lane >> 4;
    const int srow = lane >> 2;
    const int scol = (lane & 3) * 8;

    float* xb = xbp + (size_t)kh * NROWS * D_STATE;

    f32x4 acc[4] = {};

    for (int k0 = kb; k0 < kb + D_INNER / 2; k0 += BK) {
        const ushort_t* ga = xc + (size_t)(bm + 16 * wid + srow) * D_INNER + k0 + scol;
        __builtin_amdgcn_global_load_lds((gvoid_t*)ga, (lvoid_t*)(As + wid * 512), 16, 0, 0);
        #pragma unroll
        for (int ii = 0; ii < 2; ++ii) {
            int i = wid * 2 + ii;
            const ushort_t* gb = Bw + (size_t)(16 * i + srow) * D_INNER + k0 + scol;
            __builtin_amdgcn_global_load_lds((gvoid_t*)gb, (lvoid_t*)(Bs + i * 512), 16, 0, 0);
        }
        __syncthreads();

        bf16x8 a = *reinterpret_cast<const bf16x8*>(&As[(wid * 16 + r16) * BK + g * 8]);
        #pragma unroll
        for (int n = 0; n < 4; ++n) {
            bf16x8 bv = *reinterpret_cast<const bf16x8*>(&Bs[(n * 16 + r16) * BK + g * 8]);
            acc[n] = __builtin_amdgcn_mfma_f32_16x16x32_bf16(a, bv, acc[n], 0, 0, 0);
        }
        __syncthreads();
    }

    #pragma unroll
    for (int n = 0; n < 4; ++n) {
        int col  = n * 16 + r16;
        int row0 = bm + wid * 16 + g * 4;
        #pragma unroll
        for (int jj = 0; jj < 4; ++jj)
            xb[(size_t)(row0 + jj) * D_STATE + col] = acc[n][jj];
    }
}

// ---------------------------------------------------------------------------
// Speculative chunked tanh scan (overlap-save), C=W=16 (r22 proven).
// ---------------------------------------------------------------------------
#define SCAN_C 16
#define SCAN_W 16
#define NCHUNK (SEQ / SCAN_C)   // 128

__global__ __launch_bounds__(64) void scan_kernel(const float* __restrict__ xb0,
                                                  const float* __restrict__ xb1,
                                                  const float* __restrict__ A,
                                                  ushort_t* __restrict__ hall)
{
    using f32x4 = __attribute__((ext_vector_type(4))) float;

    __shared__ float xs0[(SCAN_C + SCAN_W) * D_STATE];
    __shared__ float xs1[(SCAN_C + SCAN_W) * D_STATE];
    __shared__ float hs[D_STATE];

    const int blk = blockIdx.x;
    const int b = blk >> 7;
    const int c = blk & (NCHUNK - 1);
    const int j = threadIdx.x;

    const int t0     = (c == 0) ? 0 : (c * SCAN_C - SCAN_W);
    const int warm   = c * SCAN_C - t0;        // 0 or 16
    const int nsteps = warm + SCAN_C;          // 16 or 32

    f32x4 areg[16];
    {
        const f32x4* arow = reinterpret_cast<const f32x4*>(A + j * D_STATE);
        #pragma unroll
        for (int q = 0; q < 16; ++q) areg[q] = arow[q];
    }

    const float* src0 = xb0 + ((size_t)b * SEQ + t0) * D_STATE;
    const float* src1 = xb1 + ((size_t)b * SEQ + t0) * D_STATE;
    ushort_t*    dst  = hall + ((size_t)b * SEQ + c * SCAN_C) * D_STATE;

    const int nld = nsteps * D_STATE / 256;
    for (int i = 0; i < nld; ++i) {
        __builtin_amdgcn_global_load_lds((gvoid_t*)(src0 + i * 256 + j * 4),
                                         (lvoid_t*)(&xs0[i * 256]), 16, 0, 0);
        __builtin_amdgcn_global_load_lds((gvoid_t*)(src1 + i * 256 + j * 4),
                                         (lvoid_t*)(&xs1[i * 256]), 16, 0, 0);
    }
    asm volatile("s_waitcnt vmcnt(0)" ::: "memory");

    hs[j] = 0.f;
    float h = 0.f;
    const f32x4* hp = reinterpret_cast<const f32x4*>(hs);

#define SCAN_STEP(t)                                                     \
    {                                                                    \
        float xv = xs0[(t) * D_STATE + j] + xs1[(t) * D_STATE + j];      \
        f32x4 a0 = {xv, 0.f, 0.f, 0.f}, a1 = {0.f, 0.f, 0.f, 0.f};      \
        _Pragma("unroll")                                                \
        for (int q = 0; q < 16; q += 2) {                                \
            a0 += areg[q + 0] * hp[q + 0];                               \
            a1 += areg[q + 1] * hp[q + 1];                               \
        }                                                                \
        f32x4 s4 = a0 + a1;                                              \
        float s = (s4[0] + s4[1]) + (s4[2] + s4[3]);                     \
        float e = __expf(2.f * s);                                       \
        h = 1.f - 2.f * __builtin_amdgcn_rcpf(e + 1.f);                  \
        hs[j] = h;                                                       \
    }

    for (int t = 0; t < warm; ++t) {
        SCAN_STEP(t);
    }
    for (int t = warm; t < nsteps; ++t) {
        SCAN_STEP(t);
        dst[(size_t)(t - warm) * D_STATE + j] = f2bf(h);
    }
#undef SCAN_STEP
}

// ---------------------------------------------------------------------------
// ymul via MFMA with LDS-transposed epilogue: Y = H @ C^T; x_out = (Y +
// xc*D) * silu_gate -> bf16.  After MFMA, acc is bounced through the freed
// 32KB staging buffer (f32, rotate-swizzled) in two 64-row passes so each
// thread owns 32 CONTIGUOUS cols -> ushort8 loads/stores (coalesced, ~2x
// fewer VMEM instrs than the scattered 2B version).
// ---------------------------------------------------------------------------
__global__ __launch_bounds__(256) void ymul_mfma(
    const ushort_t* __restrict__ Hbf,
    const ushort_t* __restrict__ Cbf,
    const float* __restrict__ Dv,
    const ushort_t* __restrict__ xc,
    const ushort_t* __restrict__ xg,
    ushort_t* __restrict__ xout)
{
    using bf16x8 = __attribute__((ext_vector_type(8))) short;
    using f32x4  = __attribute__((ext_vector_type(4))) float;

    constexpr int ARB  = 8;
    constexpr int ABLK = 16;
    constexpr int NBLK = 32;

    __shared__ ushort_t Tb[NBLK * 512];   // 32 KB; reused as f32 Y-buffer
    __shared__ float Dl[128];

    float* Yb = reinterpret_cast<float*>(Tb);   // [64][128] f32 per pass

    const int tid  = threadIdx.x;
    const int lane = tid & 63;
    const int wid  = tid >> 6;
    const int bm   = blockIdx.y * 128;
    const int bn   = blockIdx.x * 128;
    const int wr   = (wid >> 1) * 64;
    const int wc   = (wid & 1) * 64;
    const int r16  = lane & 15;
    const int g    = lane >> 4;
    const int srow = lane >> 2;
    const int scg  = ((lane & 3) ^ (srow & 3)) * 8;
    const int rg   = (g ^ (r16 & 3)) * 8;

    #pragma unroll
    for (int i = wid; i < NBLK; i += 4) {
        const ushort_t* gsrc;
        if (i < ABLK) {
            int kh = i / ARB, rb = i % ARB;
            gsrc = Hbf + (size_t)(bm + 16 * rb + srow) * D_STATE + kh * 32 + scg;
        } else {
            int j = i - ABLK;
            int kh = j / ARB, rb = j % ARB;
            gsrc = Cbf + (size_t)(bn + 16 * rb + srow) * D_STATE + kh * 32 + scg;
        }
        __builtin_amdgcn_global_load_lds((gvoid_t*)gsrc, (lvoid_t*)(&Tb[i * 512]), 16, 0, 0);
    }
    if (tid < 32)
        reinterpret_cast<float4*>(Dl)[tid] = reinterpret_cast<const float4*>(Dv + bn)[tid];
    __syncthreads();

    f32x4 acc[4][4] = {};
    bf16x8 af[4][2], bfr[4][2];
    #pragma unroll
    for (int kk = 0; kk < 2; ++kk) {
        #pragma unroll
        for (int m = 0; m < 4; ++m)
            af[m][kk] = *reinterpret_cast<const bf16x8*>(
                &Tb[(kk * ARB + (wr >> 4) + m) * 512 + r16 * 32 + rg]);
        #pragma unroll
        for (int n = 0; n < 4; ++n)
            bfr[n][kk] = *reinterpret_cast<const bf16x8*>(
                &Tb[(ABLK + kk * ARB + (wc >> 4) + n) * 512 + r16 * 32 + rg]);
    }
    #pragma unroll
    for (int kk = 0; kk < 2; ++kk)
        #pragma unroll
        for (int m = 0; m < 4; ++m)
            #pragma unroll
            for (int n = 0; n < 4; ++n)
                acc[m][n] = __builtin_amdgcn_mfma_f32_16x16x32_bf16(
                    af[m][kk], bfr[n][kk], acc[m][n], 0, 0, 0);

    // epilogue: two 64-row passes through Yb
    const int rrow = tid >> 2;                 // 0..63
    const int cb   = (tid & 3) * 32;           // col base (32 cols/thread)
    #pragma unroll
    for (int pass = 0; pass < 2; ++pass) {
        __syncthreads();                       // Tb free / prev pass reads done
        if ((wid >> 1) == pass) {
            #pragma unroll
            for (int m = 0; m < 4; ++m) {
                #pragma unroll
                for (int n = 0; n < 4; ++n) {
                    int col = wc + n * 16 + r16;
                    #pragma unroll
                    for (int jj = 0; jj < 4; ++jj) {
                        int row_l = m * 16 + g * 4 + jj;
                        int sc = (col & ~31) + (((col & 31) + 4 * row_l) & 31);
                        Yb[row_l * 128 + sc] = acc[m][n][jj];
                    }
                }
            }
        }
        __syncthreads();

        const int grow = bm + pass * 64 + rrow;
        const ushort_t* pxc = xc + (size_t)grow * D_INNER + bn + cb;
        const ushort_t* pxg = xg + (size_t)grow * D_INNER + bn + cb;
        ushort_t*       pxo = xout + (size_t)grow * D_INNER + bn + cb;
        #pragma unroll
        for (int ch = 0; ch < 4; ++ch) {
            int c0 = ch * 8;                   // within [0,32)
            ushort8_t xcv = *reinterpret_cast<const ushort8_t*>(pxc + c0);
            ushort8_t xgv = *reinterpret_cast<const ushort8_t*>(pxg + c0);
            ushort8_t o;
            #pragma unroll
            for (int j = 0; j < 8; ++j) {
                int sc = cb + (((c0 + j) + 4 * rrow) & 31);
                float y = Yb[rrow * 128 + sc] + bf2f(xcv[j]) * Dl[cb + c0 + j];
                o[j] = f2bf(y * bf2f(xgv[j]));
            }
            *reinterpret_cast<ushort8_t*>(pxo + c0) = o;
        }
    }
}

// ---------------------------------------------------------------------------
extern "C" void kernel_launch(void* const* d_in, const int* in_sizes, int n_in,
                              void* d_out, int out_size, void* d_ws, size_t ws_size,
                              hipStream_t stream)
{
    const float* x          = (const float*)d_in[0];
    const float* in_proj_w  = (const float*)d_in[1];
    const float* in_proj_b  = (const float*)d_in[2];
    const float* conv_w     = (const float*)d_in[3];
    const float* conv_b     = (const float*)d_in[4];
    const float* A          = (const float*)d_in[5];
    const float* B          = (const float*)d_in[6];
    const float* C          = (const float*)d_in[7];
    const float* D          = (const float*)d_in[8];
    const float* out_proj_w = (const float*)d_in[9];
    const float* out_proj_b = (const float*)d_in[10];
    float* out = (float*)d_out;

    char* ws = (char*)d_ws;
    ushort_t* xg_bf   = (ushort_t*)(ws + 0);             // 16,777,216
    ushort_t* xc_bf   = (ushort_t*)(ws + 16777216);      // 16,777,216
    ushort_t* xssm_bf = (ushort_t*)(ws + 33554432);      // 16,777,216 (dead after conv)
    ushort_t* x_bf    = (ushort_t*)(ws + 50331648);      //  8,388,608 (dead after in_proj)
    ushort_t* w1_bf   = (ushort_t*)(ws + 58720256);      //  8,388,608 (dead after in_proj)
    ushort_t* xout_bf = (ushort_t*)(ws + 50331648);      // 16,777,216 (reuses x_bf+w1_bf)
    ushort_t* w2_bf   = (ushort_t*)(ws + 67108864);      //  4,194,304
    ushort_t* B_bf    = (ushort_t*)(ws + 71303168);      //    262,144
    float*    xb01    = (float*)(ws + 71565312);         //  2,097,152 (2 partials)
    ushort_t* hall_bf = (ushort_t*)(ws + 73662464);      //    524,288
    ushort_t* C_bf    = (ushort_t*)(ws + 74186752);      //    262,144

    // 1. all f32 -> bf16 conversions, one launch (x, w1, w2, B, C)
    {
        int b0 = NROWS * D_MODEL / 1024;           // 4096
        int b1 = 2 * D_INNER * D_MODEL / 1024;     // 4096
        int b2 = D_MODEL * D_INNER / 1024;         // 2048
        int b3 = D_STATE * D_INNER / 1024;         // 128
        int b4 = D_INNER * D_STATE / 1024;         // 128
        cvt5_kernel<<<b0 + b1 + b2 + b3 + b4, 256, 0, stream>>>(
            x, x_bf, b0, in_proj_w, w1_bf, b1, out_proj_w, w2_bf, b2,
            B, B_bf, b3, C, C_bf, b4);
    }
    // 2. in_proj GEMM (8-wave 256x128 depth-2, 2-D raster — measured best)
    {
        dim3 grid(2 * D_INNER / 128, NROWS / 256);
        gemm_pipe8_inproj<<<grid, 512, 0, stream>>>(x_bf, w1_bf, in_proj_b,
                                                    xssm_bf, xg_bf, D_MODEL);
    }
    // 3. conv + silu -> bf16 (8 channels x 4 rows/thread, ushort8 IO)
    conv_silu8_kernel<<<NROWS * D_INNER / 32 / 256, 256, 0, stream>>>(xssm_bf, conv_w, conv_b, xc_bf);
    // 4. XB via bf16 MFMA, split-K 2-way (256 blocks)
    xb_mfma<<<(NROWS / 32) * 2, 128, 0, stream>>>(xc_bf, B_bf, xb01);
    // 5. speculative chunked scan (C=W=16), sums the two partials -> bf16 H
    scan_kernel<<<BATCH * NCHUNK, 64, 0, stream>>>(
        xb01, xb01 + (size_t)NROWS * D_STATE, A, hall_bf);
    // 6. ymul via MFMA (LDS-transposed coalesced epilogue) -> bf16 x_out
    {
        dim3 grid(D_INNER / 128, NROWS / 128);
        ymul_mfma<<<grid, 256, 0, stream>>>(hall_bf, C_bf, D, xc_bf, xg_bf, xout_bf);
    }
    // 7. out_proj GEMM (256-thread 128x64 KH=2, XCD-chunked — measured best)
    gemm_pipe<128, 64, 2><<<(NROWS / 128) * (D_MODEL / 64), 256, 0, stream>>>(
        xout_bf, w2_bf, out_proj_b, out, NROWS, D_MODEL, D_INNER);
}

// Round 24
// 132.294 us; speedup vs baseline: 1.0327x; 1.0327x over previous
//
#include <hip/hip_runtime.h>
#include <math.h>

#define D_MODEL 1024
#define D_INNER 2048
#define D_STATE 64
#define SEQ     2048
#define BATCH   2
#define NROWS   (BATCH*SEQ)   // 4096

typedef unsigned short ushort_t;
typedef unsigned int uint_t;

__device__ __forceinline__ float silu_f(float x) { return x / (1.f + __expf(-x)); }
__device__ __forceinline__ ushort_t f2bf(float f) {
    uint_t u = __float_as_uint(f);
    uint_t r = (u + 0x7FFFu + ((u >> 16) & 1u)) >> 16;   // RNE
    return (ushort_t)r;
}
__device__ __forceinline__ float bf2f(ushort_t u) {
    return __uint_as_float(((uint_t)u) << 16);
}

typedef __attribute__((address_space(1))) const void gvoid_t;
typedef __attribute__((address_space(3))) void lvoid_t;

template<int N> __device__ __forceinline__ void wait_vmcnt() {
    if constexpr (N == 0)      asm volatile("s_waitcnt vmcnt(0)" ::: "memory");
    else if constexpr (N == 3) asm volatile("s_waitcnt vmcnt(3)" ::: "memory");
    else if constexpr (N == 6) asm volatile("s_waitcnt vmcnt(6)" ::: "memory");
    else static_assert(N == 0, "unsupported vmcnt");
}

// ---------------------------------------------------------------------------
// Batched f32 -> bf16 conversion: 5 (src,dst) ranges in one launch.
// ---------------------------------------------------------------------------
__global__ __launch_bounds__(256) void cvt5_kernel(
    const float* __restrict__ s0, ushort_t* __restrict__ d0, int b0,
    const float* __restrict__ s1, ushort_t* __restrict__ d1, int b1,
    const float* __restrict__ s2, ushort_t* __restrict__ d2, int b2,
    const float* __restrict__ s3, ushort_t* __restrict__ d3, int b3,
    const float* __restrict__ s4, ushort_t* __restrict__ d4, int b4)
{
    int blk = blockIdx.x;
    const float* s; ushort_t* d;
    if (blk < b0)                    { s = s0; d = d0; }
    else if (blk < b0 + b1)          { s = s1; d = d1; blk -= b0; }
    else if (blk < b0 + b1 + b2)     { s = s2; d = d2; blk -= b0 + b1; }
    else if (blk < b0 + b1 + b2 + b3){ s = s3; d = d3; blk -= b0 + b1 + b2; }
    else                             { s = s4; d = d4; blk -= b0 + b1 + b2 + b3; }
    int i = (blk * 256 + threadIdx.x) * 4;
    float4 v = *reinterpret_cast<const float4*>(s + i);
    ushort4 o;
    o.x = f2bf(v.x); o.y = f2bf(v.y); o.z = f2bf(v.z); o.w = f2bf(v.w);
    *reinterpret_cast<ushort4*>(d + i) = o;
}

// ---------------------------------------------------------------------------
// in_proj GEMM: 8-wave 256x128 depth-2, 2-D raster (measured-best).
// ---------------------------------------------------------------------------
__global__ __launch_bounds__(512, 4) void gemm_pipe8_inproj(
    const ushort_t* __restrict__ Abf, const ushort_t* __restrict__ Wbf,
    const float* __restrict__ bias,
    ushort_t* __restrict__ out_x, ushort_t* __restrict__ out_g, int K)
{
    using bf16x8 = __attribute__((ext_vector_type(8))) short;
    using f32x4  = __attribute__((ext_vector_type(4))) float;

    constexpr int BMt  = 256, BNt = 128, BKt = 32;
    constexpr int ABLK = BMt / 16;            // 16
    constexpr int NBLK = (BMt + BNt) / 16;    // 24
    constexpr int TILE = (BMt + BNt) * BKt;   // 24KB
    constexpr int L    = NBLK / 8;            // 3

    __shared__ ushort_t buf[2][TILE];

    const int tid  = threadIdx.x;
    const int lane = tid & 63;
    const int wid  = tid >> 6;
    const int bm   = blockIdx.y * BMt;
    const int bn   = blockIdx.x * BNt;
    const int wr   = (wid >> 1) * 64;
    const int wc   = (wid & 1) * 64;
    const int r16  = lane & 15;
    const int g    = lane >> 4;
    const int srow = lane >> 2;
    const int scg  = ((lane & 3) ^ (srow & 3)) * 8;
    const int rg   = (g ^ (r16 & 3)) * 8;

    f32x4 acc[4][4] = {};

    auto stage = [&](int p, int k0) {
        #pragma unroll
        for (int i = wid; i < NBLK; i += 8) {
            const ushort_t* gsrc;
            if (i < ABLK)
                gsrc = Abf + (size_t)(bm + 16 * i + srow) * K + k0 + scg;
            else
                gsrc = Wbf + (size_t)(bn + 16 * (i - ABLK) + srow) * K + k0 + scg;
            __builtin_amdgcn_global_load_lds((gvoid_t*)gsrc, (lvoid_t*)(&buf[p][i * 512]), 16, 0, 0);
        }
    };

    const int NT = K / BKt;
    stage(0, 0);
    stage(1, BKt);
    wait_vmcnt<L>();
    __builtin_amdgcn_s_barrier();

    for (int t = 0; t < NT; ++t) {
        const ushort_t* Tb = &buf[t & 1][0];
        bf16x8 af[4], bfr[4];
        #pragma unroll
        for (int m = 0; m < 4; ++m)
            af[m] = *reinterpret_cast<const bf16x8*>(
                &Tb[((wr >> 4) + m) * 512 + r16 * 32 + rg]);
        #pragma unroll
        for (int n = 0; n < 4; ++n)
            bfr[n] = *reinterpret_cast<const bf16x8*>(
                &Tb[(ABLK + (wc >> 4) + n) * 512 + r16 * 32 + rg]);

        asm volatile("s_waitcnt lgkmcnt(0)" ::: "memory");
        __builtin_amdgcn_s_barrier();

        if (t + 2 < NT) stage(t & 1, (t + 2) * BKt);

        #pragma unroll
        for (int m = 0; m < 4; ++m)
            #pragma unroll
            for (int n = 0; n < 4; ++n)
                acc[m][n] = __builtin_amdgcn_mfma_f32_16x16x32_bf16(af[m], bfr[n], acc[m][n], 0, 0, 0);

        if (t + 1 < NT) {
            if (t + 2 < NT) wait_vmcnt<L>();
            else            wait_vmcnt<0>();
            __builtin_amdgcn_s_barrier();
        }
    }

    #pragma unroll
    for (int m = 0; m < 4; ++m) {
        int row0 = bm + wr + m * 16 + g * 4;
        #pragma unroll
        for (int n = 0; n < 4; ++n) {
            int col = bn + wc + n * 16 + r16;
            float b = bias[col];
            if (col < D_INNER) {
                #pragma unroll
                for (int jj = 0; jj < 4; ++jj)
                    out_x[(size_t)(row0 + jj) * D_INNER + col] = f2bf(acc[m][n][jj] + b);
            } else {
                int c2 = col - D_INNER;
                #pragma unroll
                for (int jj = 0; jj < 4; ++jj)
                    out_g[(size_t)(row0 + jj) * D_INNER + c2] = f2bf(silu_f(acc[m][n][jj] + b));
            }
        }
    }
}

// ---------------------------------------------------------------------------
// out_proj GEMM: 256-thread depth-2, KH=2, XCD-chunk swizzle (measured-best).
// ---------------------------------------------------------------------------
template <int BMt, int BNt, int KH>
__global__ __launch_bounds__(256) void gemm_pipe(
    const ushort_t* __restrict__ Abf, const ushort_t* __restrict__ Wbf,
    const float* __restrict__ bias,
    float* __restrict__ out0, int M, int N, int K)
{
    using bf16x8 = __attribute__((ext_vector_type(8))) short;
    using f32x4  = __attribute__((ext_vector_type(4))) float;

    constexpr int BKt  = 32 * KH;
    constexpr int MF   = BMt / 32;
    constexpr int NF   = BNt / 32;
    constexpr int ARB  = BMt / 16;
    constexpr int BRB  = BNt / 16;
    constexpr int ABLK = ARB * KH;
    constexpr int NBLK = (ARB + BRB) * KH;
    constexpr int TILE = (BMt + BNt) * BKt;
    constexpr int L    = NBLK / 4;

    __shared__ ushort_t buf[2][TILE];

    const int tid  = threadIdx.x;
    const int lane = tid & 63;
    const int wid  = tid >> 6;

    const int nbn  = N / BNt;
    const int bid  = blockIdx.x;
    const int nb   = (M / BMt) * nbn;
    const int cpx  = nb / 8;
    const int flat = (bid & 7) * cpx + (bid >> 3);
    const int bm   = (flat / nbn) * BMt;
    const int bn   = (flat % nbn) * BNt;

    const int wr   = (wid >> 1) * (BMt / 2);
    const int wc   = (wid & 1) * (BNt / 2);
    const int r16  = lane & 15;
    const int g    = lane >> 4;
    const int srow = lane >> 2;
    const int scg  = ((lane & 3) ^ (srow & 3)) * 8;
    const int rg   = (g ^ (r16 & 3)) * 8;

    f32x4 acc[MF][NF] = {};

    auto stage = [&](int p, int k0) {
        #pragma unroll
        for (int i = wid; i < NBLK; i += 4) {
            const ushort_t* gsrc;
            if (i < ABLK) {
                int kh = i / ARB, rb = i % ARB;
                gsrc = Abf + (size_t)(bm + 16 * rb + srow) * K + k0 + kh * 32 + scg;
            } else {
                int j = i - ABLK;
                int kh = j / BRB, rb = j % BRB;
                gsrc = Wbf + (size_t)(bn + 16 * rb + srow) * K + k0 + kh * 32 + scg;
            }
            __builtin_amdgcn_global_load_lds((gvoid_t*)gsrc, (lvoid_t*)(&buf[p][i * 512]), 16, 0, 0);
        }
    };

    const int NT = K / BKt;
    stage(0, 0);
    stage(1, BKt);
    wait_vmcnt<L>();
    __builtin_amdgcn_s_barrier();

    for (int t = 0; t < NT; ++t) {
        const ushort_t* Tb = &buf[t & 1][0];
        bf16x8 af[MF][KH], bfr[NF][KH];
        #pragma unroll
        for (int kk = 0; kk < KH; ++kk) {
            #pragma unroll
            for (int m = 0; m < MF; ++m)
                af[m][kk] = *reinterpret_cast<const bf16x8*>(
                    &Tb[(kk * ARB + (wr >> 4) + m) * 512 + r16 * 32 + rg]);
            #pragma unroll
            for (int n = 0; n < NF; ++n)
                bfr[n][kk] = *reinterpret_cast<const bf16x8*>(
                    &Tb[(ABLK + kk * BRB + (wc >> 4) + n) * 512 + r16 * 32 + rg]);
        }

        asm volatile("s_waitcnt lgkmcnt(0)" ::: "memory");
        __builtin_amdgcn_s_barrier();

        if (t + 2 < NT) stage(t & 1, (t + 2) * BKt);

        #pragma unroll
        for (int kk = 0; kk < KH; ++kk)
            #pragma unroll
            for (int m = 0; m < MF; ++m)
                #pragma unroll
                for (int n = 0; n < NF; ++n)
                    acc[m][n] = __builtin_amdgcn_mfma_f32_16x16x32_bf16(
                        af[m][kk], bfr[n][kk], acc[m][n], 0, 0, 0);

        if (t + 1 < NT) {
            if (t + 2 < NT) wait_vmcnt<L>();
            else            wait_vmcnt<0>();
            __builtin_amdgcn_s_barrier();
        }
    }

    #pragma unroll
    for (int m = 0; m < MF; ++m) {
        int row0 = bm + wr + m * 16 + g * 4;
        #pragma unroll
        for (int n = 0; n < NF; ++n) {
            int col = bn + wc + n * 16 + r16;
            float b = bias[col];
            #pragma unroll
            for (int jj = 0; jj < 4; ++jj)
                out0[(size_t)(row0 + jj) * N + col] = acc[m][n][jj] + b;
        }
    }
}

// ---------------------------------------------------------------------------
// Causal depthwise conv (D_CONV=4) + SiLU, 4 channels x 4 time-rows/thread.
// ---------------------------------------------------------------------------
__global__ __launch_bounds__(256) void conv_silu4_kernel(
    const ushort_t* __restrict__ xssm,
    const float* __restrict__ conv_w,
    const float* __restrict__ conv_b,
    ushort_t* __restrict__ xc)
{
    int idx = blockIdx.x * 256 + threadIdx.x;
    int cg = idx & (D_INNER / 4 - 1);
    int rg = idx >> 9;
    int c  = cg * 4;
    int r4 = rg * 4;
    int s4 = r4 & (SEQ - 1);

    float4 wv[4];
    #pragma unroll
    for (int cc = 0; cc < 4; ++cc)
        wv[cc] = *reinterpret_cast<const float4*>(conv_w + (c + cc) * 4);
    float4 bv = *reinterpret_cast<const float4*>(conv_b + c);
    float bias[4] = {bv.x, bv.y, bv.z, bv.w};

    float xin[7][4];
    #pragma unroll
    for (int rr = 0; rr < 7; ++rr) {
        if (s4 > 0 || rr >= 3) {
            ushort4 v = *reinterpret_cast<const ushort4*>(xssm + (size_t)(r4 + rr - 3) * D_INNER + c);
            xin[rr][0] = bf2f(v.x); xin[rr][1] = bf2f(v.y);
            xin[rr][2] = bf2f(v.z); xin[rr][3] = bf2f(v.w);
        } else {
            xin[rr][0] = xin[rr][1] = xin[rr][2] = xin[rr][3] = 0.f;
        }
    }

    #pragma unroll
    for (int i = 0; i < 4; ++i) {
        float acc[4] = {bias[0], bias[1], bias[2], bias[3]};
        #pragma unroll
        for (int dt = 0; dt < 4; ++dt) {
            int rr = i + 3 - dt;
            acc[0] += (&wv[0].x)[3 - dt] * xin[rr][0];
            acc[1] += (&wv[1].x)[3 - dt] * xin[rr][1];
            acc[2] += (&wv[2].x)[3 - dt] * xin[rr][2];
            acc[3] += (&wv[3].x)[3 - dt] * xin[rr][3];
        }
        ushort4 h;
        h.x = f2bf(silu_f(acc[0]));
        h.y = f2bf(silu_f(acc[1]));
        h.z = f2bf(silu_f(acc[2]));
        h.w = f2bf(silu_f(acc[3]));
        *reinterpret_cast<ushort4*>(xc + (size_t)(r4 + i) * D_INNER + c) = h;
    }
}

// ---------------------------------------------------------------------------
// XB split-K: partial[kh] = xconv(.,kh*1024:+1024) @ B^T  -> (4096,64) f32.
// 256 blocks (128 row-blocks x 2 k-halves), 128 threads.
// ---------------------------------------------------------------------------
#define BK 32
__global__ __launch_bounds__(128) void xb_mfma(
    const ushort_t* __restrict__ xc, const ushort_t* __restrict__ Bw,
    float* __restrict__ xbp)
{
    using bf16x8 = __attribute__((ext_vector_type(8))) short;
    using f32x4  = __attribute__((ext_vector_type(4))) float;

    __shared__ ushort_t As[32 * BK];
    __shared__ ushort_t Bs[64 * BK];

    const int tid  = threadIdx.x;
    const int lane = tid & 63;
    const int wid  = tid >> 6;
    const int kh   = blockIdx.x & 1;
    const int bm   = (blockIdx.x >> 1) * 32;
    const int kb   = kh * (D_INNER / 2);
    const int r16  = lane & 15;
    const int g    = lane >> 4;
    const int srow = lane >> 2;
    const int scol = (lane & 3) * 8;

    float* xb = xbp + (size_t)kh * NROWS * D_STATE;

    f32x4 acc[4] = {};

    for (int k0 = kb; k0 < kb + D_INNER / 2; k0 += BK) {
        const ushort_t* ga = xc + (size_t)(bm + 16 * wid + srow) * D_INNER + k0 + scol;
        __builtin_amdgcn_global_load_lds((gvoid_t*)ga, (lvoid_t*)(As + wid * 512), 16, 0, 0);
        #pragma unroll
        for (int ii = 0; ii < 2; ++ii) {
            int i = wid * 2 + ii;
            const ushort_t* gb = Bw + (size_t)(16 * i + srow) * D_INNER + k0 + scol;
            __builtin_amdgcn_global_load_lds((gvoid_t*)gb, (lvoid_t*)(Bs + i * 512), 16, 0, 0);
        }
        __syncthreads();

        bf16x8 a = *reinterpret_cast<const bf16x8*>(&As[(wid * 16 + r16) * BK + g * 8]);
        #pragma unroll
        for (int n = 0; n < 4; ++n) {
            bf16x8 bv = *reinterpret_cast<const bf16x8*>(&Bs[(n * 16 + r16) * BK + g * 8]);
            acc[n] = __builtin_amdgcn_mfma_f32_16x16x32_bf16(a, bv, acc[n], 0, 0, 0);
        }
        __syncthreads();
    }

    #pragma unroll
    for (int n = 0; n < 4; ++n) {
        int col  = n * 16 + r16;
        int row0 = bm + wid * 16 + g * 4;
        #pragma unroll
        for (int jj = 0; jj < 4; ++jj)
            xb[(size_t)(row0 + jj) * D_STATE + col] = acc[n][jj];
    }
}

// ---------------------------------------------------------------------------
// Speculative chunked tanh scan (overlap-save), C=W=16 (32 serial steps).
// Reads TWO split-K partials, sums during the step.  Emits bf16 H.
// ---------------------------------------------------------------------------
#define SCAN_C 16
#define SCAN_W 16
#define NCHUNK (SEQ / SCAN_C)   // 128

__global__ __launch_bounds__(64) void scan_kernel(const float* __restrict__ xb0,
                                                  const float* __restrict__ xb1,
                                                  const float* __restrict__ A,
                                                  ushort_t* __restrict__ hall)
{
    using f32x4 = __attribute__((ext_vector_type(4))) float;

    __shared__ float xs0[(SCAN_C + SCAN_W) * D_STATE];   // 8 KB
    __shared__ float xs1[(SCAN_C + SCAN_W) * D_STATE];   // 8 KB
    __shared__ float hs[D_STATE];

    const int blk = blockIdx.x;
    const int b = blk >> 7;          // / NCHUNK
    const int c = blk & (NCHUNK - 1);
    const int j = threadIdx.x;

    const int t0     = (c == 0) ? 0 : (c * SCAN_C - SCAN_W);
    const int warm   = c * SCAN_C - t0;        // 0 or 16
    const int nsteps = warm + SCAN_C;          // 16 or 32

    f32x4 areg[16];
    {
        const f32x4* arow = reinterpret_cast<const f32x4*>(A + j * D_STATE);
        #pragma unroll
        for (int q = 0; q < 16; ++q) areg[q] = arow[q];
    }

    const float* src0 = xb0 + ((size_t)b * SEQ + t0) * D_STATE;
    const float* src1 = xb1 + ((size_t)b * SEQ + t0) * D_STATE;
    ushort_t*    dst  = hall + ((size_t)b * SEQ + c * SCAN_C) * D_STATE;

    const int nld = nsteps * D_STATE / 256;    // 4 or 8 x 1KB per partial
    for (int i = 0; i < nld; ++i) {
        __builtin_amdgcn_global_load_lds((gvoid_t*)(src0 + i * 256 + j * 4),
                                         (lvoid_t*)(&xs0[i * 256]), 16, 0, 0);
        __builtin_amdgcn_global_load_lds((gvoid_t*)(src1 + i * 256 + j * 4),
                                         (lvoid_t*)(&xs1[i * 256]), 16, 0, 0);
    }
    asm volatile("s_waitcnt vmcnt(0)" ::: "memory");

    hs[j] = 0.f;
    float h = 0.f;
    const f32x4* hp = reinterpret_cast<const f32x4*>(hs);

#define SCAN_STEP(t)                                                     \
    {                                                                    \
        float xv = xs0[(t) * D_STATE + j] + xs1[(t) * D_STATE + j];      \
        f32x4 a0 = {xv, 0.f, 0.f, 0.f}, a1 = {0.f, 0.f, 0.f, 0.f};      \
        _Pragma("unroll")                                                \
        for (int q = 0; q < 16; q += 2) {                                \
            a0 += areg[q + 0] * hp[q + 0];                               \
            a1 += areg[q + 1] * hp[q + 1];                               \
        }                                                                \
        f32x4 s4 = a0 + a1;                                              \
        float s = (s4[0] + s4[1]) + (s4[2] + s4[3]);                     \
        float e = __expf(2.f * s);                                       \
        h = 1.f - 2.f * __builtin_amdgcn_rcpf(e + 1.f);                  \
        hs[j] = h;                                                       \
    }

    for (int t = 0; t < warm; ++t) {
        SCAN_STEP(t);
    }
    for (int t = warm; t < nsteps; ++t) {
        SCAN_STEP(t);
        dst[(size_t)(t - warm) * D_STATE + j] = f2bf(h);
    }
#undef SCAN_STEP
}

// ---------------------------------------------------------------------------
// ymul via MFMA: Y = H(4096x64) @ C(2048x64)^T, fused epilogue (r22 proven).
// ---------------------------------------------------------------------------
__global__ __launch_bounds__(256) void ymul_mfma(
    const ushort_t* __restrict__ Hbf,
    const ushort_t* __restrict__ Cbf,
    const float* __restrict__ Dv,
    const ushort_t* __restrict__ xc,
    const ushort_t* __restrict__ xg,
    ushort_t* __restrict__ xout)
{
    using bf16x8 = __attribute__((ext_vector_type(8))) short;
    using f32x4  = __attribute__((ext_vector_type(4))) float;

    constexpr int ARB  = 8;
    constexpr int ABLK = 16;
    constexpr int NBLK = 32;

    __shared__ ushort_t Tb[NBLK * 512];   // 32 KB

    const int tid  = threadIdx.x;
    const int lane = tid & 63;
    const int wid  = tid >> 6;
    const int bm   = blockIdx.y * 128;
    const int bn   = blockIdx.x * 128;
    const int wr   = (wid >> 1) * 64;
    const int wc   = (wid & 1) * 64;
    const int r16  = lane & 15;
    const int g    = lane >> 4;
    const int srow = lane >> 2;
    const int scg  = ((lane & 3) ^ (srow & 3)) * 8;
    const int rg   = (g ^ (r16 & 3)) * 8;

    #pragma unroll
    for (int i = wid; i < NBLK; i += 4) {
        const ushort_t* gsrc;
        if (i < ABLK) {
            int kh = i / ARB, rb = i % ARB;
            gsrc = Hbf + (size_t)(bm + 16 * rb + srow) * D_STATE + kh * 32 + scg;
        } else {
            int j = i - ABLK;
            int kh = j / ARB, rb = j % ARB;
            gsrc = Cbf + (size_t)(bn + 16 * rb + srow) * D_STATE + kh * 32 + scg;
        }
        __builtin_amdgcn_global_load_lds((gvoid_t*)gsrc, (lvoid_t*)(&Tb[i * 512]), 16, 0, 0);
    }
    __syncthreads();

    f32x4 acc[4][4] = {};
    bf16x8 af[4][2], bfr[4][2];
    #pragma unroll
    for (int kk = 0; kk < 2; ++kk) {
        #pragma unroll
        for (int m = 0; m < 4; ++m)
            af[m][kk] = *reinterpret_cast<const bf16x8*>(
                &Tb[(kk * ARB + (wr >> 4) + m) * 512 + r16 * 32 + rg]);
        #pragma unroll
        for (int n = 0; n < 4; ++n)
            bfr[n][kk] = *reinterpret_cast<const bf16x8*>(
                &Tb[(ABLK + kk * ARB + (wc >> 4) + n) * 512 + r16 * 32 + rg]);
    }
    #pragma unroll
    for (int kk = 0; kk < 2; ++kk)
        #pragma unroll
        for (int m = 0; m < 4; ++m)
            #pragma unroll
            for (int n = 0; n < 4; ++n)
                acc[m][n] = __builtin_amdgcn_mfma_f32_16x16x32_bf16(
                    af[m][kk], bfr[n][kk], acc[m][n], 0, 0, 0);

    #pragma unroll
    for (int m = 0; m < 4; ++m) {
        int row0 = bm + wr + m * 16 + g * 4;
        #pragma unroll
        for (int n = 0; n < 4; ++n) {
            int col = bn + wc + n * 16 + r16;
            float dv = Dv[col];
            #pragma unroll
            for (int jj = 0; jj < 4; ++jj) {
                size_t idx = (size_t)(row0 + jj) * D_INNER + col;
                float y = acc[m][n][jj] + bf2f(xc[idx]) * dv;
                xout[idx] = f2bf(y * bf2f(xg[idx]));
            }
        }
    }
}

// ---------------------------------------------------------------------------
extern "C" void kernel_launch(void* const* d_in, const int* in_sizes, int n_in,
                              void* d_out, int out_size, void* d_ws, size_t ws_size,
                              hipStream_t stream)
{
    const float* x          = (const float*)d_in[0];
    const float* in_proj_w  = (const float*)d_in[1];
    const float* in_proj_b  = (const float*)d_in[2];
    const float* conv_w     = (const float*)d_in[3];
    const float* conv_b     = (const float*)d_in[4];
    const float* A          = (const float*)d_in[5];
    const float* B          = (const float*)d_in[6];
    const float* C          = (const float*)d_in[7];
    const float* D          = (const float*)d_in[8];
    const float* out_proj_w = (const float*)d_in[9];
    const float* out_proj_b = (const float*)d_in[10];
    float* out = (float*)d_out;

    char* ws = (char*)d_ws;
    ushort_t* xg_bf   = (ushort_t*)(ws + 0);             // 16,777,216
    ushort_t* xc_bf   = (ushort_t*)(ws + 16777216);      // 16,777,216
    ushort_t* xssm_bf = (ushort_t*)(ws + 33554432);      // 16,777,216 (dead after conv)
    ushort_t* x_bf    = (ushort_t*)(ws + 50331648);      //  8,388,608 (dead after in_proj)
    ushort_t* w1_bf   = (ushort_t*)(ws + 58720256);      //  8,388,608 (dead after in_proj)
    ushort_t* xout_bf = (ushort_t*)(ws + 50331648);      // 16,777,216 (reuses x_bf+w1_bf)
    ushort_t* w2_bf   = (ushort_t*)(ws + 67108864);      //  4,194,304
    ushort_t* B_bf    = (ushort_t*)(ws + 71303168);      //    262,144
    float*    xb01    = (float*)(ws + 71565312);         //  2,097,152 (2 partials)
    ushort_t* hall_bf = (ushort_t*)(ws + 73662464);      //    524,288
    ushort_t* C_bf    = (ushort_t*)(ws + 74186752);      //    262,144

    // 1. all f32 -> bf16 conversions, one launch (x, w1, w2, B, C)
    {
        int b0 = NROWS * D_MODEL / 1024;           // 4096
        int b1 = 2 * D_INNER * D_MODEL / 1024;     // 4096
        int b2 = D_MODEL * D_INNER / 1024;         // 2048
        int b3 = D_STATE * D_INNER / 1024;         // 128
        int b4 = D_INNER * D_STATE / 1024;         // 128
        cvt5_kernel<<<b0 + b1 + b2 + b3 + b4, 256, 0, stream>>>(
            x, x_bf, b0, in_proj_w, w1_bf, b1, out_proj_w, w2_bf, b2,
            B, B_bf, b3, C, C_bf, b4);
    }
    // 2. in_proj GEMM (8-wave 256x128 depth-2, 2-D raster — measured best)
    {
        dim3 grid(2 * D_INNER / 128, NROWS / 256);
        gemm_pipe8_inproj<<<grid, 512, 0, stream>>>(x_bf, w1_bf, in_proj_b,
                                                    xssm_bf, xg_bf, D_MODEL);
    }
    // 3. conv + silu -> bf16 (4 channels x 4 rows/thread)
    conv_silu4_kernel<<<NROWS * D_INNER / 16 / 256, 256, 0, stream>>>(xssm_bf, conv_w, conv_b, xc_bf);
    // 4. XB via bf16 MFMA, split-K 2-way (256 blocks)
    xb_mfma<<<(NROWS / 32) * 2, 128, 0, stream>>>(xc_bf, B_bf, xb01);
    // 5. speculative chunked scan (C=W=16), sums the two partials -> bf16 H
    scan_kernel<<<BATCH * NCHUNK, 64, 0, stream>>>(
        xb01, xb01 + (size_t)NROWS * D_STATE, A, hall_bf);
    // 6. ymul via MFMA (fused D-skip + gate) -> bf16 x_out
    {
        dim3 grid(D_INNER / 128, NROWS / 128);
        ymul_mfma<<<grid, 256, 0, stream>>>(hall_bf, C_bf, D, xc_bf, xg_bf, xout_bf);
    }
    // 7. out_proj GEMM (256-thread 128x64 KH=2, XCD-chunked — measured best)
    gemm_pipe<128, 64, 2><<<(NROWS / 128) * (D_MODEL / 64), 256, 0, stream>>>(
        xout_bf, w2_bf, out_proj_b, out, NROWS, D_MODEL, D_INNER);
}